// Round 12
// baseline (195.652 us; speedup 1.0000x reference)
//
#include <hip/hip_runtime.h>
#include <hip/hip_bf16.h>
#include <cstdint>

typedef __bf16 bhalf;
typedef __bf16 bhalf8 __attribute__((ext_vector_type(8)));
typedef float f32x4 __attribute__((ext_vector_type(4)));

enum { EPI_Z2=0, EPI_UVH=1, EPI_BIAS=2, EPI_QK=3, EPI_ATTN=4, EPI_PV=5, EPI_Y=6 };

// async global->LDS, 16B per lane, LDS dest = wave-uniform base + lane*16
__device__ __forceinline__ void gl_lds16(const bhalf* g, bhalf* l) {
  __builtin_amdgcn_global_load_lds(
      (const __attribute__((address_space(1))) unsigned int*)g,
      (__attribute__((address_space(3))) unsigned int*)l,
      16, 0, 0);
}
__device__ __forceinline__ void barrier_raw() { asm volatile("s_barrier" ::: "memory"); }
#define VMW(n)  asm volatile("s_waitcnt vmcnt(" #n ")" ::: "memory")
#define LGKM0() asm volatile("s_waitcnt lgkmcnt(0)" ::: "memory")

// Staging bank swizzle (verified R4-R11: SQ_LDS_BANK_CONFLICT == 0): 16B chunk
// c of a 64B row r holds global chunk c ^ ((r>>1)&3). Write: pre-swizzled
// GLOBAL source, linear LDS dest (rule #21); read: kqs = kq ^ ((lm>>1)&3).
// Epilogue token-major C-tile swizzle: 32B chunk ^ ((row>>2)&3).
// Epilogue TRANSPOSED C-tile swizzle: element t of row c at t ^ ((c&15)<<2).

// ---------------------------------------------------------------------------
// gA: 256x256, BK=64, 8 waves (2M x 4N, wave 128x64), 2 dbufs (128 KB),
// 4 phases/K-tile of 16 MFMA, in-place region staging, VMW(4)/K-tile.
// For score / UVH. UVH: u->ub (sigmoid), v->v_fm (transposed), h->hb.
// ---------------------------------------------------------------------------
template<int EPI>
__global__ void __launch_bounds__(512, 2)
gA(const bhalf* __restrict__ A, const bhalf* __restrict__ Bw,
   void* __restrict__ Out, void* __restrict__ Out2, void* __restrict__ Out3,
   const float* __restrict__ bias, const float* __restrict__ bias2,
   const float* __restrict__ bias3,
   int N, int K, long sA, long sB, long sO, long sAuxf, float scale)
{
  constexpr int KSL = 256*64;     // 16 KB per k-slice plane
  constexpr int REG = 2*KSL;      // 32 KB (one K-tile of A or B)
  constexpr int DBUF = 2*REG;     // 64 KB
  __shared__ __align__(16) char lds[2*DBUF];   // 128 KB

  const int gx = gridDim.x, gy = gridDim.y;
  const int nwg = gx*gy;
  const int flat = blockIdx.y*gx + blockIdx.x;
  const int q8 = nwg>>3, r8 = nwg&7, xcd = flat&7, o8 = flat>>3;
  const int wsw = (xcd<r8 ? xcd*(q8+1) : r8*(q8+1)+(xcd-r8)*q8) + o8;
  const int bx = wsw % gx, by = wsw / gx;
  const int m0 = by*256, n0 = bx*256;
  const int bz = blockIdx.z;

  const bhalf* Ab = A + (long)bz*sA;
  const bhalf* Bb = Bw + (long)bz*sB;

  const int tid = threadIdx.x, wid = tid>>6, lane = tid&63;
  const int lm = lane&15, kq = lane>>4;
  const int wm = wid>>2, wn = wid&3;
  const int srow = lane>>2;
  const int csw = ((lane&3) ^ ((lane>>3)&3)) * 8;
  const int kqs = kq ^ ((lm>>1)&3);

  f32x4 acc[8][4];
  #pragma unroll
  for (int i=0;i<8;i++)
    #pragma unroll
    for (int j=0;j<4;j++) acc[i][j] = f32x4{0.f,0.f,0.f,0.f};

  auto stageA = [&](int kt){                     // 4 loads/wave
    char* base = lds + (kt&1)*DBUF;
    const int k0 = kt*64;
    #pragma unroll
    for (int h=0; h<2; h++)
      #pragma unroll
      for (int ksl=0; ksl<2; ksl++){
        bhalf* d = (bhalf*)(base + ksl*KSL + (h*128 + wid*16)*64);
        gl_lds16(Ab + (long)(m0 + h*128 + wid*16 + srow)*K + k0 + ksl*32 + csw, d);
      }
  };
  auto stageB = [&](int kt){                     // 4 loads/wave
    char* base = lds + (kt&1)*DBUF + REG;
    const int k0 = kt*64;
    #pragma unroll
    for (int h=0; h<2; h++)
      #pragma unroll
      for (int ksl=0; ksl<2; ksl++){
        bhalf* d = (bhalf*)(base + ksl*KSL + (h*128 + wid*16)*64);
        gl_lds16(Bb + (long)(n0 + h*128 + wid*16 + srow)*K + k0 + ksl*32 + csw, d);
      }
  };

  bhalf8 af[4][2], bf[4][2];
  auto readA = [&](int kt, int ih){
    char* base = lds + (kt&1)*DBUF;
    #pragma unroll
    for (int i2=0;i2<4;i2++)
      #pragma unroll
      for (int ksl=0;ksl<2;ksl++)
        af[i2][ksl] = *(const bhalf8*)(base + ksl*KSL + (wm*128 + ih*64 + i2*16 + lm)*64 + kqs*16);
  };
  auto readB = [&](int kt, int jh){
    char* base = lds + (kt&1)*DBUF + REG;
    #pragma unroll
    for (int j2=0;j2<2;j2++)
      #pragma unroll
      for (int ksl=0;ksl<2;ksl++)
        bf[jh*2+j2][ksl] = *(const bhalf8*)(base + ksl*KSL + (wn*64 + jh*32 + j2*16 + lm)*64 + kqs*16);
  };
  auto mfma16 = [&](int ih, int jh){
    __builtin_amdgcn_s_setprio(1);
    #pragma unroll
    for (int i2=0;i2<4;i2++)
      #pragma unroll
      for (int j2=0;j2<2;j2++)
        #pragma unroll
        for (int ksl=0;ksl<2;ksl++)
          acc[ih*4+i2][jh*2+j2] = __builtin_amdgcn_mfma_f32_16x16x32_bf16(
              af[i2][ksl], bf[jh*2+j2][ksl], acc[ih*4+i2][jh*2+j2], 0,0,0);
    __builtin_amdgcn_s_setprio(0);
  };

  const int NT = K>>6;
  stageA(0); stageB(0); stageA(1);               // 12 loads
  for (int kt=0; kt<NT; ++kt){
    if (kt==NT-1) { VMW(0); } else { VMW(4); }
    barrier_raw();
    readA(kt,0); readB(kt,0);
    if (kt+1<NT) stageB(kt+1);
    mfma16(0,0);
    barrier_raw();
    readB(kt,1);
    mfma16(0,1);
    barrier_raw();
    readA(kt,1);
    mfma16(1,0);
    barrier_raw();
    if (kt+2<NT) stageA(kt+2);
    mfma16(1,1);
  }
  barrier_raw();

  // ---- epilogues ----
  if constexpr (EPI==EPI_ATTN){
    float rs[8][4];
    #pragma unroll
    for (int i=0;i<8;i++)
      #pragma unroll
      for (int r=0;r<4;r++) rs[i][r]=0.f;
    #pragma unroll
    for (int i=0;i<8;i++){
      #pragma unroll
      for (int j=0;j<4;j++){
        const int lcol = wn*64 + j*16 + lm;
        #pragma unroll
        for (int r=0;r<4;r++){
          const int lrow = wm*128 + i*16 + kq*4 + r;
          float v = acc[i][j][r];
          v *= scale; v = fmaxf(v,0.f); v = v*v;
          rs[i][r] += v;
          const int cb = lcol*2;
          const int lb = lrow*512 + (((cb>>5) ^ ((lrow>>2)&3))<<5) + (cb&31);
          *(bhalf*)(lds + lb) = (bhalf)v;
        }
      }
    }
    float* rd = (float*)Out2;
    #pragma unroll
    for (int i=0;i<8;i++){
      const int rbase = m0 + wm*128 + i*16 + kq*4;
      #pragma unroll
      for (int r=0;r<4;r++){
        float s = rs[i][r];
        s += __shfl_xor(s,1); s += __shfl_xor(s,2);
        s += __shfl_xor(s,4); s += __shfl_xor(s,8);
        if (lm==0) atomicAdd(rd + (long)bz*sAuxf + rbase + r, s);
      }
    }
    LGKM0();
    barrier_raw();
    char* obase = (char*)Out + 2*((long)bz*sO + (long)m0*N + n0);
    const int ldb = N*2;
    #pragma unroll
    for (int it=0; it<16; ++it){
      const int g = (it*512 + tid)*16;
      const int row = g >> 9, off = g & 511;
      const int lb = row*512 + (((off>>5) ^ ((row>>2)&3))<<5) + (off&31);
      uint4 val = *(const uint4*)(lds + lb);
      *(uint4*)(obase + (long)row*ldb + off) = val;
    }
  }
  if constexpr (EPI==EPI_UVH){
    const int seg = n0 >> 10;                    // 0=u, 1=v, 2=h
    const float* bv = (seg==0) ? bias : (seg==1) ? bias2 : bias3;
    const int bc0 = n0 - ((seg==0) ? 0 : (seg==1) ? 1024 : 2048);
    #pragma unroll
    for (int i=0;i<8;i++){
      #pragma unroll
      for (int j=0;j<4;j++){
        const int lcol = wn*64 + j*16 + lm;
        #pragma unroll
        for (int r=0;r<4;r++){
          const int lrow = wm*128 + i*16 + kq*4 + r;
          float v = acc[i][j][r] + bv[bc0 + lcol];
          if (seg==1){
            // transposed store for v_fm: row=vcol, elem=token, XOR-swizzled
            const int lb = lcol*512 + 2*(lrow ^ ((lcol&15)<<2));
            *(bhalf*)(lds + lb) = (bhalf)v;
          } else {
            if (seg==0) v = 1.f/(1.f + __expf(-v));
            const int cb = lcol*2;
            const int lb = lrow*512 + (((cb>>5) ^ ((lrow>>2)&3))<<5) + (cb&31);
            *(bhalf*)(lds + lb) = (bhalf)v;
          }
        }
      }
    }
    LGKM0();
    barrier_raw();
    if (seg==1){
      // v_fm [B][1024][2048]: row = vcol, 512B = 256 tokens per row-segment
      char* vb = (char*)Out2 + 2*((long)(m0>>11)*1024*2048 + (long)(n0-1024)*2048 + (m0 & 2047));
      #pragma unroll
      for (int it=0; it<16; ++it){
        const int g = (it*512 + tid)*16;
        const int row = g >> 9, off = g & 511;
        const int t0 = off >> 1;
        const int s = (row&15)<<2;
        unsigned long long lo = *(const unsigned long long*)(lds + row*512 + 2*(t0^s));
        unsigned long long hi = *(const unsigned long long*)(lds + row*512 + 2*((t0+4)^s));
        char* dst = vb + (long)row*4096 + off;
        ((unsigned long long*)dst)[0] = lo;
        ((unsigned long long*)dst)[1] = hi;
      }
    } else {
      char* obase; int ldb;
      if (seg==0){ obase = (char*)Out + 2*((long)m0*1024 + n0); ldb = 2048; }
      else       { obase = (char*)Out3 + 2*((long)m0*512 + (n0-2048)); ldb = 1024; }
      #pragma unroll
      for (int it=0; it<16; ++it){
        const int g = (it*512 + tid)*16;
        const int row = g >> 9, off = g & 511;
        const int lb = row*512 + (((off>>5) ^ ((row>>2)&3))<<5) + (off&31);
        uint4 val = *(const uint4*)(lds + lb);
        *(uint4*)(obase + (long)row*ldb + off) = val;
      }
    }
  }
  (void)scale; (void)bias; (void)bias2; (void)bias3; (void)Out3; (void)N;
}

// ---------------------------------------------------------------------------
// gB: 256x128, BK=64, 8 waves (4M x 2N, wave 64x64), ring-of-3 dbufs (144 KB),
// 4 phases/K-tile of 8 MFMA (reads spread per-phase), stage kt+2 at ph1,
// VMW(6)/K-tile. For PV / QK.
// ---------------------------------------------------------------------------
template<int EPI>
__global__ void __launch_bounds__(512, 2)
gB(const bhalf* __restrict__ A, const bhalf* __restrict__ Bw,
   void* __restrict__ Out, void* __restrict__ Out2,
   const bhalf* __restrict__ auxb, const float* __restrict__ auxf,
   int N, int K, long sB, float scale, int rowshift)
{
  constexpr int KSLA = 256*64;    // 16 KB
  constexpr int KSLB = 128*64;    // 8 KB
  constexpr int REGA = 2*KSLA;    // 32 KB
  constexpr int DBUF = REGA + 2*KSLB;   // 48 KB
  __shared__ __align__(16) char lds[3*DBUF];   // 144 KB

  const int gx = gridDim.x, gy = gridDim.y;
  const int nwg = gx*gy;
  const int flat = blockIdx.y*gx + blockIdx.x;
  const int q8 = nwg>>3, r8 = nwg&7, xcd = flat&7, o8 = flat>>3;
  const int wsw = (xcd<r8 ? xcd*(q8+1) : r8*(q8+1)+(xcd-r8)*q8) + o8;
  const int bx = wsw % gx, by = wsw / gx;
  const int m0 = by*256, n0 = bx*128;

  const bhalf* Ab = A;
  const bhalf* Bb = Bw + (rowshift ? (long)(m0>>rowshift)*sB : 0);

  const int tid = threadIdx.x, wid = tid>>6, lane = tid&63;
  const int lm = lane&15, kq = lane>>4;
  const int wm = wid>>1, wn = wid&1;
  const int srow = lane>>2;
  const int csw = ((lane&3) ^ ((lane>>3)&3)) * 8;
  const int kqs = kq ^ ((lm>>1)&3);

  f32x4 acc[4][4];
  #pragma unroll
  for (int i=0;i<4;i++)
    #pragma unroll
    for (int j=0;j<4;j++) acc[i][j] = f32x4{0.f,0.f,0.f,0.f};

  auto stageAB = [&](int kt){                    // 6 loads/wave
    char* base = lds + (kt%3)*DBUF;
    const int k0 = kt*64;
    #pragma unroll
    for (int h=0; h<2; h++)
      #pragma unroll
      for (int ksl=0; ksl<2; ksl++){
        bhalf* d = (bhalf*)(base + ksl*KSLA + (h*128 + wid*16)*64);
        gl_lds16(Ab + (long)(m0 + h*128 + wid*16 + srow)*K + k0 + ksl*32 + csw, d);
      }
    #pragma unroll
    for (int ksl=0; ksl<2; ksl++){
      bhalf* d = (bhalf*)(base + REGA + ksl*KSLB + (wid*16)*64);
      gl_lds16(Bb + (long)(n0 + wid*16 + srow)*K + k0 + ksl*32 + csw, d);
    }
  };

  bhalf8 af[4], bf[2];
  auto readA = [&](int kt, int ksl){
    char* base = lds + (kt%3)*DBUF;
    #pragma unroll
    for (int i2=0;i2<4;i2++)
      af[i2] = *(const bhalf8*)(base + ksl*KSLA + (wm*64 + i2*16 + lm)*64 + kqs*16);
  };
  auto readB = [&](int kt, int jh, int ksl){
    char* base = lds + (kt%3)*DBUF + REGA;
    #pragma unroll
    for (int j2=0;j2<2;j2++)
      bf[j2] = *(const bhalf8*)(base + ksl*KSLB + (wn*64 + jh*32 + j2*16 + lm)*64 + kqs*16);
  };
  auto mfma8 = [&](int jh){
    __builtin_amdgcn_s_setprio(1);
    #pragma unroll
    for (int i2=0;i2<4;i2++)
      #pragma unroll
      for (int j2=0;j2<2;j2++)
        acc[i2][jh*2+j2] = __builtin_amdgcn_mfma_f32_16x16x32_bf16(
            af[i2], bf[j2], acc[i2][jh*2+j2], 0,0,0);
    __builtin_amdgcn_s_setprio(0);
  };

  const int NT = K>>6;
  stageAB(0); stageAB(1);                        // 12 loads
  for (int kt=0; kt<NT; ++kt){
    // ph1: (jh0, ksl0)
    if (kt==NT-1) { VMW(0); } else { VMW(6); }
    barrier_raw();
    readA(kt,0); readB(kt,0,0);
    if (kt+2<NT) stageAB(kt+2);
    mfma8(0);
    // ph2: (jh1, ksl0)
    barrier_raw();
    readB(kt,1,0);
    mfma8(1);
    // ph3: (jh0, ksl1)
    barrier_raw();
    readA(kt,1); readB(kt,0,1);
    mfma8(0);
    // ph4: (jh1, ksl1)
    barrier_raw();
    readB(kt,1,1);
    mfma8(1);
  }
  barrier_raw();

  // ---- epilogue: C-tile 256x128 bf16 in LDS (256B rows) -> coalesced ----
  char* obase; int ldb;
  if constexpr (EPI==EPI_PV){
    obase = (char*)Out + 2*((long)m0*1024 + n0); ldb = 2048;
  }
  if constexpr (EPI==EPI_QK){
    bool qh = n0 < 512;
    obase = (char*)(qh?Out:Out2) + 2*((long)m0*512 + (n0 - (qh?0:512)));
    ldb = 1024;
  }
  #pragma unroll
  for (int i=0;i<4;i++){
    #pragma unroll
    for (int j=0;j<4;j++){
      const int lcol = wn*64 + j*16 + lm;
      #pragma unroll
      for (int r=0;r<4;r++){
        const int lrow = wm*64 + i*16 + kq*4 + r;
        float v = acc[i][j][r];
        if constexpr (EPI==EPI_PV){
          const int rowg = m0 + lrow;
          float den = auxf[rowg];
          v *= __builtin_amdgcn_rcpf(den + 1e-8f);
          v *= (float)auxb[(long)rowg*1024 + n0 + lcol];
        }
        const int cb = lcol*2;
        const int lb = lrow*256 + (((cb>>5) ^ ((lrow>>2)&3))<<5) + (cb&31);
        *(bhalf*)(lds + lb) = (bhalf)v;
      }
    }
  }
  LGKM0();
  barrier_raw();
  #pragma unroll
  for (int it=0; it<8; ++it){
    const int g = (it*512 + tid)*16;
    const int row = g >> 8, off = g & 255;
    const int lb = row*256 + (((off>>5) ^ ((row>>2)&3))<<5) + (off&31);
    uint4 val = *(const uint4*)(lds + lb);
    *(uint4*)(obase + (long)row*ldb + off) = val;
  }
  (void)scale; (void)auxb; (void)auxf; (void)N;
}

// ---------------------------------------------------------------------------
// g4k: 128x128 tile, 4 waves (2M x 2N, wave 64x64), BK=64, 2 dbufs (64 KB),
// 2-ahead in-place staging, VMW(8)/K-tile. For z2 / y.
// EPI_Y fuses the residual add: out[b][c][n] = x + y (fp32, transposed tile).
// ---------------------------------------------------------------------------
template<int EPI>
__global__ void __launch_bounds__(256, 2)
g4k(const bhalf* __restrict__ A, const bhalf* __restrict__ Bw,
    void* __restrict__ Out,
    const float* __restrict__ bias,
    const bhalf* __restrict__ auxb,
    const float* __restrict__ xadd,
    int M, int N, int K)
{
  constexpr int KSL = 256*64;     // 16 KB plane: A rows 0-127, B rows 128-255
  constexpr int DBUF = 2*KSL;     // 32 KB
  __shared__ __align__(16) char lds[2*DBUF];   // 64 KB

  const int gx = gridDim.x, gy = gridDim.y;
  const int nwg = gx*gy;
  const int flat = blockIdx.y*gx + blockIdx.x;
  const int q8 = nwg>>3, r8 = nwg&7, xcd = flat&7, o8 = flat>>3;
  const int w = (xcd<r8 ? xcd*(q8+1) : r8*(q8+1)+(xcd-r8)*q8) + o8;
  const int bx = w % gx, by = w / gx;
  const int m0 = by*128, n0 = bx*128;

  const int tid = threadIdx.x;
  const int wid = tid>>6, lane = tid&63;
  const int lm = lane&15, kq = lane>>4;
  const int wm = wid>>1, wn = wid&1;
  const int srow = lane>>2;
  const int csw = ((lane&3) ^ ((lane>>3)&3))*8;
  const int kqs = kq ^ ((lm>>1)&3);

  f32x4 acc[4][4];
  #pragma unroll
  for (int i=0;i<4;i++)
    #pragma unroll
    for (int j=0;j<4;j++) acc[i][j] = f32x4{0.f,0.f,0.f,0.f};

  auto stage = [&](int kt){                      // 8 loads/wave
    char* base = lds + (kt&1)*DBUF;
    const int k0 = kt*64;
    #pragma unroll
    for (int c=0;c<4;c++){
      const int r0 = c*64 + wid*16;
      #pragma unroll
      for (int ksl=0; ksl<2; ksl++){
        bhalf* d = (bhalf*)(base + ksl*KSL + r0*64);
        const bhalf* g = (r0 < 128)
          ? A  + (long)(m0 + r0 + srow)*K + k0 + ksl*32 + csw
          : Bw + (long)(n0 + r0 - 128 + srow)*K + k0 + ksl*32 + csw;
        gl_lds16(g, d);
      }
    }
  };

  bhalf8 af[4][2], bf[4][2];
  auto readA = [&](int kt){
    char* base = lds + (kt&1)*DBUF;
    #pragma unroll
    for (int i2=0;i2<4;i2++)
      #pragma unroll
      for (int ksl=0;ksl<2;ksl++)
        af[i2][ksl] = *(const bhalf8*)(base + ksl*KSL + (wm*64 + i2*16 + lm)*64 + kqs*16);
  };
  auto readB = [&](int kt, int jh){
    char* base = lds + (kt&1)*DBUF;
    #pragma unroll
    for (int j2=0;j2<2;j2++)
      #pragma unroll
      for (int ksl=0;ksl<2;ksl++)
        bf[jh*2+j2][ksl] = *(const bhalf8*)(base + ksl*KSL + (128 + wn*64 + jh*32 + j2*16 + lm)*64 + kqs*16);
  };
  auto mfma16 = [&](int jh){
    __builtin_amdgcn_s_setprio(1);
    #pragma unroll
    for (int i2=0;i2<4;i2++)
      #pragma unroll
      for (int j2=0;j2<2;j2++)
        #pragma unroll
        for (int ksl=0;ksl<2;ksl++)
          acc[i2][jh*2+j2] = __builtin_amdgcn_mfma_f32_16x16x32_bf16(
              af[i2][ksl], bf[jh*2+j2][ksl], acc[i2][jh*2+j2], 0,0,0);
    __builtin_amdgcn_s_setprio(0);
  };

  const int NT = K>>6;
  stage(0); stage(1);
  for (int kt=0; kt<NT; ++kt){
    if (kt==NT-1) { VMW(0); } else { VMW(8); }
    barrier_raw();
    readA(kt); readB(kt,0);
    mfma16(0);
    barrier_raw();
    readB(kt,1);
    if (kt+2<NT) stage(kt+2);
    mfma16(1);
  }
  barrier_raw();

  // ---- epilogues ----
  if constexpr (EPI==EPI_Y){
    #pragma unroll
    for (int i=0;i<4;i++){
      #pragma unroll
      for (int j=0;j<4;j++){
        const int lcol = wn*64 + j*16 + lm;
        #pragma unroll
        for (int r=0;r<4;r++){
          const int lrow = wm*64 + i*16 + kq*4 + r;
          float v = acc[i][j][r] + bias[n0 + lcol];
          const int lb = lcol*512 + 4*(lrow ^ ((lcol&15)<<2));
          *(float*)(lds + lb) = v;
        }
      }
    }
    LGKM0();
    barrier_raw();
    const int b = m0 >> 11, nb = m0 & 2047;
    float* ob = (float*)Out + ((long)b*512 + n0)*2048 + nb;
    const float* xb = xadd + ((long)b*512 + n0)*2048 + nb;
    #pragma unroll
    for (int it=0; it<16; ++it){
      const int g = (it*256 + tid)*16;
      const int row = g >> 9, off = g & 511;
      const int t0 = off >> 2;
      const int s = (row&15)<<2;
      f32x4 vv = *(const f32x4*)(lds + row*512 + 4*(t0^s));
      f32x4 xx = *(const f32x4*)(xb + (long)row*2048 + t0);
      *(f32x4*)(ob + (long)row*2048 + t0) = vv + xx;
    }
  } else {
    char* obase = (char*)Out + 2*((long)m0*N + n0);
    const int ldb = N*2;
    #pragma unroll
    for (int i=0;i<4;i++){
      #pragma unroll
      for (int j=0;j<4;j++){
        const int lcol = wn*64 + j*16 + lm;
        #pragma unroll
        for (int r=0;r<4;r++){
          const int lrow = wm*64 + i*16 + kq*4 + r;
          float v = acc[i][j][r];
          if constexpr (EPI==EPI_Z2)
            v += (float)auxb[(long)(m0+lrow)*N + n0 + lcol];
          if constexpr (EPI==EPI_BIAS)
            v += bias[n0 + lcol];
          const int cb = lcol*2;
          const int lb = lrow*256 + (((cb>>5) ^ ((lrow>>2)&3))<<5) + (cb&31);
          *(bhalf*)(lds + lb) = (bhalf)v;
        }
      }
    }
    LGKM0();
    barrier_raw();
    #pragma unroll
    for (int it=0; it<8; ++it){
      const int g = (it*256 + tid)*16;
      const int row = g >> 8, off = g & 255;
      const int lb = row*256 + (((off>>5) ^ ((row>>2)&3))<<5) + (off&31);
      uint4 val = *(const uint4*)(lds + lb);
      *(uint4*)(obase + (long)row*ldb + off) = val;
    }
  }
  (void)M; (void)xadd; (void)bias; (void)auxb;
}

// ---------------------------------------------------------------------------
struct CvtArgs { const float* src[7]; bhalf* dst[7]; int n[7]; };
__global__ void cvt_multi(CvtArgs a) {
  int seg = blockIdx.y;
  int i = (blockIdx.x*256 + threadIdx.x)*4;
  if (i >= a.n[seg]) return;
  float4 f = *(const float4*)(a.src[seg] + i);
  bhalf* d = a.dst[seg] + i;
  d[0]=(bhalf)f.x; d[1]=(bhalf)f.y; d[2]=(bhalf)f.z; d[3]=(bhalf)f.w;
}

__global__ void gn_part(const float* __restrict__ x, float* __restrict__ ps, float* __restrict__ pss) {
  int b = blockIdx.y;
  const float* xb = x + (long)b*(512*2048);
  float s=0.f, ss=0.f;
  #pragma unroll
  for (int it=0; it<8; it++){
    int idx = ((it*128 + blockIdx.x)*256 + threadIdx.x)*4;
    float4 f = *(const float4*)(xb + idx);
    s  += f.x+f.y+f.z+f.w;
    ss += f.x*f.x+f.y*f.y+f.z*f.z+f.w*f.w;
  }
  for (int off=32; off; off>>=1){ s += __shfl_xor(s,off); ss += __shfl_xor(ss,off); }
  __shared__ float ls[4], lss[4];
  int wid = threadIdx.x>>6, lane = threadIdx.x&63;
  if (lane==0){ ls[wid]=s; lss[wid]=ss; }
  __syncthreads();
  if (threadIdx.x==0){
    s = ls[0]+ls[1]+ls[2]+ls[3]; ss = lss[0]+lss[1]+lss[2]+lss[3];
    ps[b*128 + blockIdx.x] = s; pss[b*128 + blockIdx.x] = ss;
  }
}

__global__ void gn_final(const float* __restrict__ ps, const float* __restrict__ pss,
                         float* __restrict__ stats) {
  int b = blockIdx.x;
  float s = ps[b*128 + threadIdx.x], ss = pss[b*128 + threadIdx.x];
  for (int off=32; off; off>>=1){ s += __shfl_xor(s,off); ss += __shfl_xor(ss,off); }
  __shared__ float l0[2], l1[2];
  int wid = threadIdx.x>>6, lane = threadIdx.x&63;
  if (lane==0){ l0[wid]=s; l1[wid]=ss; }
  __syncthreads();
  if (threadIdx.x==0){
    s = l0[0]+l0[1]; ss = l1[0]+l1[1];
    float mean = s*(1.f/1048576.f);
    float var  = ss*(1.f/1048576.f) - mean*mean;
    stats[b*2] = mean; stats[b*2+1] = rsqrtf(var + 1e-8f);
  }
}

__global__ void norm_dw_T(const float* __restrict__ x, const float* __restrict__ stats,
                          const float* __restrict__ dw_w,
                          bhalf* __restrict__ zT, bhalf* __restrict__ dwT) {
  int b = blockIdx.z, n0 = blockIdx.x*32, c0 = blockIdx.y*32;
  float mean = stats[b*2], rstd = stats[b*2+1];
  __shared__ float zs[32][35];
  int tx = threadIdx.x, ty = threadIdx.y;
  #pragma unroll
  for (int r=0;r<4;r++){
    int c = c0 + ty + r*8;
    for (int cc=tx; cc<34; cc+=32){
      int n = n0 - 1 + cc;
      float v = 0.f;
      if (n>=0 && n<2048) v = (x[((long)b*512 + c)*2048 + n] - mean)*rstd;
      zs[ty + r*8][cc] = v;
    }
  }
  __syncthreads();
  float w0 = dw_w[(c0+tx)*3+0], w1 = dw_w[(c0+tx)*3+1], w2 = dw_w[(c0+tx)*3+2];
  #pragma unroll
  for (int r=0;r<4;r++){
    int ln = ty + r*8;
    float z = zs[tx][ln+1];
    float d = w0*zs[tx][ln] + w1*zs[tx][ln+1] + w2*zs[tx][ln+2];
    long o = ((long)b*2048 + n0 + ln)*512 + c0 + tx;
    zT[o] = (bhalf)z; dwT[o] = (bhalf)d;
  }
}

// ---------------------------------------------------------------------------
extern "C" void kernel_launch(void* const* d_in, const int* in_sizes, int n_in,
                              void* d_out, int out_size, void* d_ws, size_t ws_size,
                              hipStream_t stream) {
  (void)in_sizes; (void)n_in; (void)out_size; (void)ws_size;
  const float* x    = (const float*)d_in[0];
  const float* dw_w = (const float*)d_in[1];
  const float* pw_w = (const float*)d_in[2];
  const float* u_w  = (const float*)d_in[3];
  const float* u_b  = (const float*)d_in[4];
  const float* v_w  = (const float*)d_in[5];
  const float* v_b  = (const float*)d_in[6];
  const float* h_w  = (const float*)d_in[7];
  const float* h_b  = (const float*)d_in[8];
  const float* q_w  = (const float*)d_in[9];
  const float* k_w  = (const float*)d_in[10];
  const float* o_w  = (const float*)d_in[11];
  const float* o_b  = (const float*)d_in[12];
  float* out = (float*)d_out;

  char* ws = (char*)d_ws;
  size_t off = 0;
  auto alloc = [&](size_t bytes) -> void* {
    void* p = ws + off; off = (off + bytes + 255) & ~(size_t)255; return p;
  };

  float* ps    = (float*)alloc(4*128*4);
  float* pss   = (float*)alloc(4*128*4);
  float* stats = (float*)alloc(4*2*4);
  float* rden  = (float*)alloc(4*2048*4);
  bhalf* wb_pw  = (bhalf*)alloc(512*512*2);
  bhalf* wb_uvh = (bhalf*)alloc((size_t)2560*512*2);   // u|v|h concat
  bhalf* wb_qk  = (bhalf*)alloc((size_t)1024*512*2);
  bhalf* wb_o   = (bhalf*)alloc((size_t)512*1024*2);
  const size_t ACT = (size_t)4*2048*512;
  bhalf* zT   = (bhalf*)alloc(ACT*2);       // reused as qb
  bhalf* dwT  = (bhalf*)alloc(ACT*2);       // reused as kb
  bhalf* z2T  = (bhalf*)alloc(ACT*2);
  bhalf* ub   = (bhalf*)alloc(ACT*2*2);     // [B,N,1024]
  bhalf* v_fm = (bhalf*)alloc(ACT*2*2);     // [B,1024,2048]
  bhalf* hb   = (bhalf*)alloc(ACT*2);
  bhalf* wsc  = (bhalf*)alloc((size_t)4*2048*2048*2);
  bhalf* uav  = (bhalf*)alloc(ACT*2*2);
  bhalf* qb = zT;  bhalf* kb = dwT;

  // 0. zero attention-denominator accumulators
  hipMemsetAsync(rden, 0, 4*2048*4, stream);

  // 1. weights -> bf16 (u|v|h and q|k concatenated)
  CvtArgs ca;
  ca.src[0]=pw_w; ca.dst[0]=wb_pw;            ca.n[0]=512*512;
  ca.src[1]=u_w;  ca.dst[1]=wb_uvh;           ca.n[1]=1024*512;
  ca.src[2]=v_w;  ca.dst[2]=wb_uvh+1024*512;  ca.n[2]=1024*512;
  ca.src[3]=h_w;  ca.dst[3]=wb_uvh+2048*512;  ca.n[3]=512*512;
  ca.src[4]=q_w;  ca.dst[4]=wb_qk;            ca.n[4]=512*512;
  ca.src[5]=k_w;  ca.dst[5]=wb_qk+512*512;    ca.n[5]=512*512;
  ca.src[6]=o_w;  ca.dst[6]=wb_o;             ca.n[6]=512*1024;
  cvt_multi<<<dim3(512,7), 256, 0, stream>>>(ca);

  // 2-3. GroupNorm stats
  gn_part<<<dim3(128,4), 256, 0, stream>>>(x, ps, pss);
  gn_final<<<dim3(4), 128, 0, stream>>>(ps, pss, stats);

  // 4. normalize + dw conv + transpose -> zT, dwT
  norm_dw_T<<<dim3(64,16,4), dim3(32,8), 0, stream>>>(x, stats, dw_w, zT, dwT);

  const float iscl = 0.044194173824159216f;   // 1/sqrt(512)
  // 5. z2 = z + dw @ pw^T                (g4k 128^2)
  g4k<EPI_Z2><<<dim3(4,64,1), 256, 0, stream>>>(dwT, wb_pw, z2T,
      nullptr, zT, nullptr, 8192, 512, 512);
  // 6. [u|v|h] = z2 @ [u_w|v_w|h_w]^T + b   (gA; u->ub, v->v_fm, h->hb)
  gA<EPI_UVH><<<dim3(10,32,1), 512, 0, stream>>>(z2T, wb_uvh, ub, v_fm, hb,
      u_b, v_b, h_b, 2560, 512, 0, 0, 0, 0, 0.f);
  // 7. [q|k] = h @ [q_w|k_w]^T           (gB 256x128, 4-phase)
  gB<EPI_QK><<<dim3(8,32,1), 512, 0, stream>>>(hb, wb_qk, qb, kb,
      nullptr, nullptr, 1024, 512, 0, 0.f, 0);
  // 8. w = relu(q@k^T * scale)^2 + fused row-sum atomics into rden  (gA)
  gA<EPI_ATTN><<<dim3(8,8,4), 512, 0, stream>>>(qb, kb, wsc, rden, nullptr,
      nullptr, nullptr, nullptr, 2048, 512,
      (long)2048*512, (long)2048*512, (long)2048*2048, 2048, iscl);
  // 9. uav = u * (w @ v_fm^T) / (den+eps)   (gB 4-phase, batch in M)
  gB<EPI_PV><<<dim3(8,32,1), 512, 0, stream>>>(wsc, v_fm, uav, nullptr,
      ub, rden, 1024, 2048, (long)1024*2048, 0.f, 11);
  // 10. out = x + (uav @ o_w^T + o_b)^T  (g4k, fused residual add)
  g4k<EPI_Y><<<dim3(4,64,1), 256, 0, stream>>>(uav, wb_o, out,
      o_b, nullptr, x, 8192, 512, 1024);
}

// Round 13
// 183.381 us; speedup vs baseline: 1.0669x; 1.0669x over previous
//
#include <hip/hip_runtime.h>
#include <hip/hip_bf16.h>
#include <cstdint>

typedef __bf16 bhalf;
typedef __bf16 bhalf8 __attribute__((ext_vector_type(8)));
typedef float f32x4 __attribute__((ext_vector_type(4)));

enum { EPI_Z2=0, EPI_UV=1, EPI_BIAS=2, EPI_QK=3, EPI_ATTN=4, EPI_PV=5, EPI_Y=6 };

// async global->LDS, 16B per lane, LDS dest = wave-uniform base + lane*16
__device__ __forceinline__ void gl_lds16(const bhalf* g, bhalf* l) {
  __builtin_amdgcn_global_load_lds(
      (const __attribute__((address_space(1))) unsigned int*)g,
      (__attribute__((address_space(3))) unsigned int*)l,
      16, 0, 0);
}
__device__ __forceinline__ void barrier_raw() { asm volatile("s_barrier" ::: "memory"); }
#define VMW(n)  asm volatile("s_waitcnt vmcnt(" #n ")" ::: "memory")
#define LGKM0() asm volatile("s_waitcnt lgkmcnt(0)" ::: "memory")

// Staging bank swizzle (verified R4-R12: SQ_LDS_BANK_CONFLICT == 0): 16B chunk
// c of a 64B row r holds global chunk c ^ ((r>>1)&3). Write: pre-swizzled
// GLOBAL source, linear LDS dest (rule #21); read: kqs = kq ^ ((lm>>1)&3).
// Epilogue token-major C-tile swizzle: 32B chunk ^ ((row>>2)&3).
// Epilogue TRANSPOSED C-tile swizzle: element t of row c at t ^ ((c&15)<<2).

// ---------------------------------------------------------------------------
// gA: 256x256, BK=64, 8 waves (2M x 4N, wave 128x64), 2 dbufs (128 KB),
// 4 phases/K-tile of 16 MFMA, in-place region staging, VMW(4)/K-tile.
// For score / UV. UV: u->ub (sigmoid), v->v_fm (transposed direct).
// ---------------------------------------------------------------------------
template<int EPI>
__global__ void __launch_bounds__(512, 2)
gA(const bhalf* __restrict__ A, const bhalf* __restrict__ Bw,
   void* __restrict__ Out, void* __restrict__ Out2,
   const float* __restrict__ bias, const float* __restrict__ bias2,
   int N, int K, long sA, long sB, long sO, long sAuxf, float scale)
{
  constexpr int KSL = 256*64;     // 16 KB per k-slice plane
  constexpr int REG = 2*KSL;      // 32 KB (one K-tile of A or B)
  constexpr int DBUF = 2*REG;     // 64 KB
  __shared__ __align__(16) char lds[2*DBUF];   // 128 KB

  const int gx = gridDim.x, gy = gridDim.y;
  const int nwg = gx*gy;
  const int flat = blockIdx.y*gx + blockIdx.x;
  const int q8 = nwg>>3, r8 = nwg&7, xcd = flat&7, o8 = flat>>3;
  const int wsw = (xcd<r8 ? xcd*(q8+1) : r8*(q8+1)+(xcd-r8)*q8) + o8;
  const int bx = wsw % gx, by = wsw / gx;
  const int m0 = by*256, n0 = bx*256;
  const int bz = blockIdx.z;

  const bhalf* Ab = A + (long)bz*sA;
  const bhalf* Bb = Bw + (long)bz*sB;

  const int tid = threadIdx.x, wid = tid>>6, lane = tid&63;
  const int lm = lane&15, kq = lane>>4;
  const int wm = wid>>2, wn = wid&3;
  const int srow = lane>>2;
  const int csw = ((lane&3) ^ ((lane>>3)&3)) * 8;
  const int kqs = kq ^ ((lm>>1)&3);

  f32x4 acc[8][4];
  #pragma unroll
  for (int i=0;i<8;i++)
    #pragma unroll
    for (int j=0;j<4;j++) acc[i][j] = f32x4{0.f,0.f,0.f,0.f};

  auto stageA = [&](int kt){                     // 4 loads/wave
    char* base = lds + (kt&1)*DBUF;
    const int k0 = kt*64;
    #pragma unroll
    for (int h=0; h<2; h++)
      #pragma unroll
      for (int ksl=0; ksl<2; ksl++){
        bhalf* d = (bhalf*)(base + ksl*KSL + (h*128 + wid*16)*64);
        gl_lds16(Ab + (long)(m0 + h*128 + wid*16 + srow)*K + k0 + ksl*32 + csw, d);
      }
  };
  auto stageB = [&](int kt){                     // 4 loads/wave
    char* base = lds + (kt&1)*DBUF + REG;
    const int k0 = kt*64;
    #pragma unroll
    for (int h=0; h<2; h++)
      #pragma unroll
      for (int ksl=0; ksl<2; ksl++){
        bhalf* d = (bhalf*)(base + ksl*KSL + (h*128 + wid*16)*64);
        gl_lds16(Bb + (long)(n0 + h*128 + wid*16 + srow)*K + k0 + ksl*32 + csw, d);
      }
  };

  bhalf8 af[4][2], bf[4][2];
  auto readA = [&](int kt, int ih){
    char* base = lds + (kt&1)*DBUF;
    #pragma unroll
    for (int i2=0;i2<4;i2++)
      #pragma unroll
      for (int ksl=0;ksl<2;ksl++)
        af[i2][ksl] = *(const bhalf8*)(base + ksl*KSL + (wm*128 + ih*64 + i2*16 + lm)*64 + kqs*16);
  };
  auto readB = [&](int kt, int jh){
    char* base = lds + (kt&1)*DBUF + REG;
    #pragma unroll
    for (int j2=0;j2<2;j2++)
      #pragma unroll
      for (int ksl=0;ksl<2;ksl++)
        bf[jh*2+j2][ksl] = *(const bhalf8*)(base + ksl*KSL + (wn*64 + jh*32 + j2*16 + lm)*64 + kqs*16);
  };
  auto mfma16 = [&](int ih, int jh){
    __builtin_amdgcn_s_setprio(1);
    #pragma unroll
    for (int i2=0;i2<4;i2++)
      #pragma unroll
      for (int j2=0;j2<2;j2++)
        #pragma unroll
        for (int ksl=0;ksl<2;ksl++)
          acc[ih*4+i2][jh*2+j2] = __builtin_amdgcn_mfma_f32_16x16x32_bf16(
              af[i2][ksl], bf[jh*2+j2][ksl], acc[ih*4+i2][jh*2+j2], 0,0,0);
    __builtin_amdgcn_s_setprio(0);
  };

  const int NT = K>>6;
  stageA(0); stageB(0); stageA(1);               // 12 loads
  for (int kt=0; kt<NT; ++kt){
    if (kt==NT-1) { VMW(0); } else { VMW(4); }
    barrier_raw();
    readA(kt,0); readB(kt,0);
    if (kt+1<NT) stageB(kt+1);
    mfma16(0,0);
    barrier_raw();
    readB(kt,1);
    mfma16(0,1);
    barrier_raw();
    readA(kt,1);
    mfma16(1,0);
    barrier_raw();
    if (kt+2<NT) stageA(kt+2);
    mfma16(1,1);
  }
  barrier_raw();

  // ---- epilogues ----
  if constexpr (EPI==EPI_ATTN){
    float rs[8][4];
    #pragma unroll
    for (int i=0;i<8;i++)
      #pragma unroll
      for (int r=0;r<4;r++) rs[i][r]=0.f;
    #pragma unroll
    for (int i=0;i<8;i++){
      #pragma unroll
      for (int j=0;j<4;j++){
        const int lcol = wn*64 + j*16 + lm;
        #pragma unroll
        for (int r=0;r<4;r++){
          const int lrow = wm*128 + i*16 + kq*4 + r;
          float v = acc[i][j][r];
          v *= scale; v = fmaxf(v,0.f); v = v*v;
          rs[i][r] += v;
          const int cb = lcol*2;
          const int lb = lrow*512 + (((cb>>5) ^ ((lrow>>2)&3))<<5) + (cb&31);
          *(bhalf*)(lds + lb) = (bhalf)v;
        }
      }
    }
    float* rd = (float*)Out2;
    #pragma unroll
    for (int i=0;i<8;i++){
      const int rbase = m0 + wm*128 + i*16 + kq*4;
      #pragma unroll
      for (int r=0;r<4;r++){
        float s = rs[i][r];
        s += __shfl_xor(s,1); s += __shfl_xor(s,2);
        s += __shfl_xor(s,4); s += __shfl_xor(s,8);
        if (lm==0) atomicAdd(rd + (long)bz*sAuxf + rbase + r, s);
      }
    }
    LGKM0();
    barrier_raw();
    char* obase = (char*)Out + 2*((long)bz*sO + (long)m0*N + n0);
    const int ldb = N*2;
    #pragma unroll
    for (int it=0; it<16; ++it){
      const int g = (it*512 + tid)*16;
      const int row = g >> 9, off = g & 511;
      const int lb = row*512 + (((off>>5) ^ ((row>>2)&3))<<5) + (off&31);
      uint4 val = *(const uint4*)(lds + lb);
      *(uint4*)(obase + (long)row*ldb + off) = val;
    }
  }
  if constexpr (EPI==EPI_UV){
    const bool uh = n0 < 1024;
    const float* bv = uh ? bias : bias2;
    const int bc0 = uh ? n0 : n0-1024;
    #pragma unroll
    for (int i=0;i<8;i++){
      #pragma unroll
      for (int j=0;j<4;j++){
        const int lcol = wn*64 + j*16 + lm;
        #pragma unroll
        for (int r=0;r<4;r++){
          const int lrow = wm*128 + i*16 + kq*4 + r;
          float v = acc[i][j][r] + bv[bc0 + lcol];
          if (uh){
            v = 1.f/(1.f + __expf(-v));
            const int cb = lcol*2;
            const int lb = lrow*512 + (((cb>>5) ^ ((lrow>>2)&3))<<5) + (cb&31);
            *(bhalf*)(lds + lb) = (bhalf)v;
          } else {
            const int lb = lcol*512 + 2*(lrow ^ ((lcol&15)<<2));
            *(bhalf*)(lds + lb) = (bhalf)v;
          }
        }
      }
    }
    LGKM0();
    barrier_raw();
    if (uh){
      char* obase = (char*)Out + 2*((long)m0*1024 + n0);
      #pragma unroll
      for (int it=0; it<16; ++it){
        const int g = (it*512 + tid)*16;
        const int row = g >> 9, off = g & 511;
        const int lb = row*512 + (((off>>5) ^ ((row>>2)&3))<<5) + (off&31);
        uint4 val = *(const uint4*)(lds + lb);
        *(uint4*)(obase + (long)row*2048 + off) = val;
      }
    } else {
      char* vb = (char*)Out2 + 2*((long)(m0>>11)*1024*2048 + (long)(n0-1024)*2048 + (m0 & 2047));
      #pragma unroll
      for (int it=0; it<16; ++it){
        const int g = (it*512 + tid)*16;
        const int row = g >> 9, off = g & 511;
        const int t0 = off >> 1;
        const int s = (row&15)<<2;
        unsigned long long lo = *(const unsigned long long*)(lds + row*512 + 2*(t0^s));
        unsigned long long hi = *(const unsigned long long*)(lds + row*512 + 2*((t0+4)^s));
        char* dst = vb + (long)row*4096 + off;
        ((unsigned long long*)dst)[0] = lo;
        ((unsigned long long*)dst)[1] = hi;
      }
    }
  }
  (void)scale; (void)bias; (void)bias2; (void)N;
}

// ---------------------------------------------------------------------------
// g4k: 128x128 tile, 4 waves (2M x 2N, wave 64x64), BK=64, 2 dbufs (64 KB ->
// 2 blocks/CU when grid >= 512), 2-ahead in-place staging, VMW(8)/K-tile.
// For z2 / h / y / QK / PV. EPI_Y fuses the residual add (fp32 transposed).
// ---------------------------------------------------------------------------
template<int EPI>
__global__ void __launch_bounds__(256, 2)
g4k(const bhalf* __restrict__ A, const bhalf* __restrict__ Bw,
    void* __restrict__ Out, void* __restrict__ Out2,
    const float* __restrict__ bias,
    const bhalf* __restrict__ auxb, const float* __restrict__ auxf,
    const float* __restrict__ xadd,
    int M, int N, int K, long sB, int rowshift)
{
  constexpr int KSL = 256*64;     // 16 KB plane: A rows 0-127, B rows 128-255
  constexpr int DBUF = 2*KSL;     // 32 KB
  __shared__ __align__(16) char lds[2*DBUF];   // 64 KB

  const int gx = gridDim.x, gy = gridDim.y;
  const int nwg = gx*gy;
  const int flat = blockIdx.y*gx + blockIdx.x;
  const int q8 = nwg>>3, r8 = nwg&7, xcd = flat&7, o8 = flat>>3;
  const int w = (xcd<r8 ? xcd*(q8+1) : r8*(q8+1)+(xcd-r8)*q8) + o8;
  const int bx = w % gx, by = w / gx;
  const int m0 = by*128, n0 = bx*128;

  const bhalf* Bb = Bw + (rowshift ? (long)(m0>>rowshift)*sB : 0);

  const int tid = threadIdx.x;
  const int wid = tid>>6, lane = tid&63;
  const int lm = lane&15, kq = lane>>4;
  const int wm = wid>>1, wn = wid&1;
  const int srow = lane>>2;
  const int csw = ((lane&3) ^ ((lane>>3)&3))*8;
  const int kqs = kq ^ ((lm>>1)&3);

  f32x4 acc[4][4];
  #pragma unroll
  for (int i=0;i<4;i++)
    #pragma unroll
    for (int j=0;j<4;j++) acc[i][j] = f32x4{0.f,0.f,0.f,0.f};

  auto stage = [&](int kt){                      // 8 loads/wave
    char* base = lds + (kt&1)*DBUF;
    const int k0 = kt*64;
    #pragma unroll
    for (int c=0;c<4;c++){
      const int r0 = c*64 + wid*16;
      #pragma unroll
      for (int ksl=0; ksl<2; ksl++){
        bhalf* d = (bhalf*)(base + ksl*KSL + r0*64);
        const bhalf* g = (r0 < 128)
          ? A  + (long)(m0 + r0 + srow)*K + k0 + ksl*32 + csw
          : Bb + (long)(n0 + r0 - 128 + srow)*K + k0 + ksl*32 + csw;
        gl_lds16(g, d);
      }
    }
  };

  bhalf8 af[4][2], bf[4][2];
  auto readA = [&](int kt){
    char* base = lds + (kt&1)*DBUF;
    #pragma unroll
    for (int i2=0;i2<4;i2++)
      #pragma unroll
      for (int ksl=0;ksl<2;ksl++)
        af[i2][ksl] = *(const bhalf8*)(base + ksl*KSL + (wm*64 + i2*16 + lm)*64 + kqs*16);
  };
  auto readB = [&](int kt, int jh){
    char* base = lds + (kt&1)*DBUF;
    #pragma unroll
    for (int j2=0;j2<2;j2++)
      #pragma unroll
      for (int ksl=0;ksl<2;ksl++)
        bf[jh*2+j2][ksl] = *(const bhalf8*)(base + ksl*KSL + (128 + wn*64 + jh*32 + j2*16 + lm)*64 + kqs*16);
  };
  auto mfma16 = [&](int jh){
    __builtin_amdgcn_s_setprio(1);
    #pragma unroll
    for (int i2=0;i2<4;i2++)
      #pragma unroll
      for (int j2=0;j2<2;j2++)
        #pragma unroll
        for (int ksl=0;ksl<2;ksl++)
          acc[i2][jh*2+j2] = __builtin_amdgcn_mfma_f32_16x16x32_bf16(
              af[i2][ksl], bf[jh*2+j2][ksl], acc[i2][jh*2+j2], 0,0,0);
    __builtin_amdgcn_s_setprio(0);
  };

  const int NT = K>>6;
  stage(0); stage(1);
  for (int kt=0; kt<NT; ++kt){
    if (kt==NT-1) { VMW(0); } else { VMW(8); }
    barrier_raw();
    readA(kt); readB(kt,0);
    mfma16(0);
    barrier_raw();
    readB(kt,1);
    if (kt+2<NT) stage(kt+2);
    mfma16(1);
  }
  barrier_raw();

  // ---- epilogues ----
  if constexpr (EPI==EPI_Y){
    #pragma unroll
    for (int i=0;i<4;i++){
      #pragma unroll
      for (int j=0;j<4;j++){
        const int lcol = wn*64 + j*16 + lm;
        #pragma unroll
        for (int r=0;r<4;r++){
          const int lrow = wm*64 + i*16 + kq*4 + r;
          float v = acc[i][j][r] + bias[n0 + lcol];
          const int lb = lcol*512 + 4*(lrow ^ ((lcol&15)<<2));
          *(float*)(lds + lb) = v;
        }
      }
    }
    LGKM0();
    barrier_raw();
    const int b = m0 >> 11, nb = m0 & 2047;
    float* ob = (float*)Out + ((long)b*512 + n0)*2048 + nb;
    const float* xb = xadd + ((long)b*512 + n0)*2048 + nb;
    #pragma unroll
    for (int it=0; it<16; ++it){
      const int g = (it*256 + tid)*16;
      const int row = g >> 9, off = g & 511;
      const int t0 = off >> 2;
      const int s = (row&15)<<2;
      f32x4 vv = *(const f32x4*)(lds + row*512 + 4*(t0^s));
      f32x4 xx = *(const f32x4*)(xb + (long)row*2048 + t0);
      *(f32x4*)(ob + (long)row*2048 + t0) = vv + xx;
    }
  } else {
    char* obase; int ldb;
    if constexpr (EPI==EPI_QK){
      bool qh = n0 < 512;
      obase = (char*)(qh?Out:Out2) + 2*((long)m0*512 + (n0 - (qh?0:512)));
      ldb = 1024;
    } else {
      obase = (char*)Out + 2*((long)m0*N + n0);
      ldb = N*2;
    }
    #pragma unroll
    for (int i=0;i<4;i++){
      #pragma unroll
      for (int j=0;j<4;j++){
        const int lcol = wn*64 + j*16 + lm;
        #pragma unroll
        for (int r=0;r<4;r++){
          const int lrow = wm*64 + i*16 + kq*4 + r;
          float v = acc[i][j][r];
          if constexpr (EPI==EPI_Z2)
            v += (float)auxb[(long)(m0+lrow)*N + n0 + lcol];
          if constexpr (EPI==EPI_BIAS)
            v += bias[n0 + lcol];
          if constexpr (EPI==EPI_PV){
            const int rowg = m0 + lrow;
            float den = auxf[rowg];
            v *= __builtin_amdgcn_rcpf(den + 1e-8f);
            v *= (float)auxb[(long)rowg*1024 + n0 + lcol];
          }
          const int cb = lcol*2;
          const int lb = lrow*256 + (((cb>>5) ^ ((lrow>>2)&3))<<5) + (cb&31);
          *(bhalf*)(lds + lb) = (bhalf)v;
        }
      }
    }
    LGKM0();
    barrier_raw();
    #pragma unroll
    for (int it=0; it<8; ++it){
      const int g = (it*256 + tid)*16;
      const int row = g >> 8, off = g & 255;
      const int lb = row*256 + (((off>>5) ^ ((row>>2)&3))<<5) + (off&31);
      uint4 val = *(const uint4*)(lds + lb);
      *(uint4*)(obase + (long)row*ldb + off) = val;
    }
  }
  (void)M; (void)xadd; (void)bias; (void)auxb; (void)auxf;
}

// ---------------------------------------------------------------------------
struct CvtArgs { const float* src[7]; bhalf* dst[7]; int n[7]; };
__global__ void cvt_multi(CvtArgs a) {
  int seg = blockIdx.y;
  int i = (blockIdx.x*256 + threadIdx.x)*4;
  if (i >= a.n[seg]) return;
  float4 f = *(const float4*)(a.src[seg] + i);
  bhalf* d = a.dst[seg] + i;
  d[0]=(bhalf)f.x; d[1]=(bhalf)f.y; d[2]=(bhalf)f.z; d[3]=(bhalf)f.w;
}

__global__ void gn_part(const float* __restrict__ x, float* __restrict__ ps, float* __restrict__ pss) {
  int b = blockIdx.y;
  const float* xb = x + (long)b*(512*2048);
  float s=0.f, ss=0.f;
  #pragma unroll
  for (int it=0; it<8; it++){
    int idx = ((it*128 + blockIdx.x)*256 + threadIdx.x)*4;
    float4 f = *(const float4*)(xb + idx);
    s  += f.x+f.y+f.z+f.w;
    ss += f.x*f.x+f.y*f.y+f.z*f.z+f.w*f.w;
  }
  for (int off=32; off; off>>=1){ s += __shfl_xor(s,off); ss += __shfl_xor(ss,off); }
  __shared__ float ls[4], lss[4];
  int wid = threadIdx.x>>6, lane = threadIdx.x&63;
  if (lane==0){ ls[wid]=s; lss[wid]=ss; }
  __syncthreads();
  if (threadIdx.x==0){
    s = ls[0]+ls[1]+ls[2]+ls[3]; ss = lss[0]+lss[1]+lss[2]+lss[3];
    ps[b*128 + blockIdx.x] = s; pss[b*128 + blockIdx.x] = ss;
  }
}

__global__ void gn_final(const float* __restrict__ ps, const float* __restrict__ pss,
                         float* __restrict__ stats) {
  int b = blockIdx.x;
  float s = ps[b*128 + threadIdx.x], ss = pss[b*128 + threadIdx.x];
  for (int off=32; off; off>>=1){ s += __shfl_xor(s,off); ss += __shfl_xor(ss,off); }
  __shared__ float l0[2], l1[2];
  int wid = threadIdx.x>>6, lane = threadIdx.x&63;
  if (lane==0){ l0[wid]=s; l1[wid]=ss; }
  __syncthreads();
  if (threadIdx.x==0){
    s = l0[0]+l0[1]; ss = l1[0]+l1[1];
    float mean = s*(1.f/1048576.f);
    float var  = ss*(1.f/1048576.f) - mean*mean;
    stats[b*2] = mean; stats[b*2+1] = rsqrtf(var + 1e-8f);
  }
}

__global__ void norm_dw_T(const float* __restrict__ x, const float* __restrict__ stats,
                          const float* __restrict__ dw_w,
                          bhalf* __restrict__ zT, bhalf* __restrict__ dwT) {
  int b = blockIdx.z, n0 = blockIdx.x*32, c0 = blockIdx.y*32;
  float mean = stats[b*2], rstd = stats[b*2+1];
  __shared__ float zs[32][35];
  int tx = threadIdx.x, ty = threadIdx.y;
  #pragma unroll
  for (int r=0;r<4;r++){
    int c = c0 + ty + r*8;
    for (int cc=tx; cc<34; cc+=32){
      int n = n0 - 1 + cc;
      float v = 0.f;
      if (n>=0 && n<2048) v = (x[((long)b*512 + c)*2048 + n] - mean)*rstd;
      zs[ty + r*8][cc] = v;
    }
  }
  __syncthreads();
  float w0 = dw_w[(c0+tx)*3+0], w1 = dw_w[(c0+tx)*3+1], w2 = dw_w[(c0+tx)*3+2];
  #pragma unroll
  for (int r=0;r<4;r++){
    int ln = ty + r*8;
    float z = zs[tx][ln+1];
    float d = w0*zs[tx][ln] + w1*zs[tx][ln+1] + w2*zs[tx][ln+2];
    long o = ((long)b*2048 + n0 + ln)*512 + c0 + tx;
    zT[o] = (bhalf)z; dwT[o] = (bhalf)d;
  }
}

// ---------------------------------------------------------------------------
extern "C" void kernel_launch(void* const* d_in, const int* in_sizes, int n_in,
                              void* d_out, int out_size, void* d_ws, size_t ws_size,
                              hipStream_t stream) {
  (void)in_sizes; (void)n_in; (void)out_size; (void)ws_size;
  const float* x    = (const float*)d_in[0];
  const float* dw_w = (const float*)d_in[1];
  const float* pw_w = (const float*)d_in[2];
  const float* u_w  = (const float*)d_in[3];
  const float* u_b  = (const float*)d_in[4];
  const float* v_w  = (const float*)d_in[5];
  const float* v_b  = (const float*)d_in[6];
  const float* h_w  = (const float*)d_in[7];
  const float* h_b  = (const float*)d_in[8];
  const float* q_w  = (const float*)d_in[9];
  const float* k_w  = (const float*)d_in[10];
  const float* o_w  = (const float*)d_in[11];
  const float* o_b  = (const float*)d_in[12];
  float* out = (float*)d_out;

  char* ws = (char*)d_ws;
  size_t off = 0;
  auto alloc = [&](size_t bytes) -> void* {
    void* p = ws + off; off = (off + bytes + 255) & ~(size_t)255; return p;
  };

  float* ps    = (float*)alloc(4*128*4);
  float* pss   = (float*)alloc(4*128*4);
  float* stats = (float*)alloc(4*2*4);
  float* rden  = (float*)alloc(4*2048*4);
  bhalf* wb_pw = (bhalf*)alloc(512*512*2);
  bhalf* wb_uv = (bhalf*)alloc((size_t)2048*512*2);
  bhalf* wb_h  = (bhalf*)alloc(512*512*2);
  bhalf* wb_qk = (bhalf*)alloc((size_t)1024*512*2);
  bhalf* wb_o  = (bhalf*)alloc((size_t)512*1024*2);
  const size_t ACT = (size_t)4*2048*512;
  bhalf* zT   = (bhalf*)alloc(ACT*2);       // reused as qb
  bhalf* dwT  = (bhalf*)alloc(ACT*2);       // reused as kb
  bhalf* z2T  = (bhalf*)alloc(ACT*2);
  bhalf* ub   = (bhalf*)alloc(ACT*2*2);     // [B,N,1024]
  bhalf* v_fm = (bhalf*)alloc(ACT*2*2);     // [B,1024,2048] (written by UV)
  bhalf* hb   = (bhalf*)alloc(ACT*2);
  bhalf* wsc  = (bhalf*)alloc((size_t)4*2048*2048*2);
  bhalf* uav  = (bhalf*)alloc(ACT*2*2);
  bhalf* qb = zT;  bhalf* kb = dwT;

  // 0. zero attention-denominator accumulators
  hipMemsetAsync(rden, 0, 4*2048*4, stream);

  // 1. weights -> bf16 (u|v and q|k concatenated)
  CvtArgs ca;
  ca.src[0]=pw_w; ca.dst[0]=wb_pw;           ca.n[0]=512*512;
  ca.src[1]=u_w;  ca.dst[1]=wb_uv;           ca.n[1]=1024*512;
  ca.src[2]=v_w;  ca.dst[2]=wb_uv+1024*512;  ca.n[2]=1024*512;
  ca.src[3]=h_w;  ca.dst[3]=wb_h;            ca.n[3]=512*512;
  ca.src[4]=q_w;  ca.dst[4]=wb_qk;           ca.n[4]=512*512;
  ca.src[5]=k_w;  ca.dst[5]=wb_qk+512*512;   ca.n[5]=512*512;
  ca.src[6]=o_w;  ca.dst[6]=wb_o;            ca.n[6]=512*1024;
  cvt_multi<<<dim3(512,7), 256, 0, stream>>>(ca);

  // 2-3. GroupNorm stats
  gn_part<<<dim3(128,4), 256, 0, stream>>>(x, ps, pss);
  gn_final<<<dim3(4), 128, 0, stream>>>(ps, pss, stats);

  // 4. normalize + dw conv + transpose -> zT, dwT
  norm_dw_T<<<dim3(64,16,4), dim3(32,8), 0, stream>>>(x, stats, dw_w, zT, dwT);

  const float iscl = 0.044194173824159216f;   // 1/sqrt(512)
  // 5. z2 = z + dw @ pw^T                (g4k 128^2)
  g4k<EPI_Z2><<<dim3(4,64,1), 256, 0, stream>>>(dwT, wb_pw, z2T, nullptr,
      nullptr, zT, nullptr, nullptr, 8192, 512, 512, 0, 0);
  // 6. [u|v] = z2 @ [u_w|v_w]^T + b      (gA; u->ub, v->v_fm direct)
  gA<EPI_UV><<<dim3(8,32,1), 512, 0, stream>>>(z2T, wb_uv, ub, v_fm,
      u_b, v_b, 2048, 512, 0, 0, 0, 0, 0.f);
  // 7. h = z2 @ h_w^T + h_b              (g4k 128^2)
  g4k<EPI_BIAS><<<dim3(4,64,1), 256, 0, stream>>>(z2T, wb_h, hb, nullptr,
      h_b, nullptr, nullptr, nullptr, 8192, 512, 512, 0, 0);
  // 8. [q|k] = h @ [q_w|k_w]^T           (g4k 128^2, 512 blocks)
  g4k<EPI_QK><<<dim3(8,64,1), 256, 0, stream>>>(hb, wb_qk, qb, kb,
      nullptr, nullptr, nullptr, nullptr, 8192, 1024, 512, 0, 0);
  // 9. w = relu(q@k^T * scale)^2 + fused row-sum atomics into rden  (gA)
  gA<EPI_ATTN><<<dim3(8,8,4), 512, 0, stream>>>(qb, kb, wsc, rden,
      nullptr, nullptr, 2048, 512,
      (long)2048*512, (long)2048*512, (long)2048*2048, 2048, iscl);
  // 10. uav = u * (w @ v_fm^T) / (den+eps)  (g4k 128^2, 512 blocks, 2/CU)
  g4k<EPI_PV><<<dim3(8,64,1), 256, 0, stream>>>(wsc, v_fm, uav, nullptr,
      nullptr, ub, rden, nullptr, 8192, 1024, 2048, (long)1024*2048, 11);
  // 11. out = x + (uav @ o_w^T + o_b)^T  (g4k, fused residual add)
  g4k<EPI_Y><<<dim3(4,64,1), 256, 0, stream>>>(uav, wb_o, out, nullptr,
      o_b, nullptr, nullptr, x, 8192, 512, 1024, 0, 0);
}